// Round 3
// baseline (20156.345 us; speedup 1.0000x reference)
//
#include <hip/hip_runtime.h>
#include <hip/hip_bf16.h>
#include <math.h>

typedef __hip_bfloat16 bf16;

#define N_LAYERS 6
#define E_DIM 128
#define H_DIM 768
#define N_HEADS 12
#define D_FFN 3072
#define SEQ_L 512
#define N_WORD 30000
#define BATCH 4
#define D_HEAD 64

// Runtime-dtype accessors: fb=1 -> input tensors are bf16, fb=0 -> fp32.
__device__ __forceinline__ float ldin(const void* p, long i, int fb) {
    return fb ? __bfloat162float(((const bf16*)p)[i]) : ((const float*)p)[i];
}
__device__ __forceinline__ void stout(void* p, long i, float v, int fb) {
    if (fb) ((bf16*)p)[i] = __float2bfloat16(v);
    else    ((float*)p)[i] = v;
}

// ---------------------------------------------------------------------------
// Dtype detect: ln1_g is all-ones. bf16 ones -> first u16 = 0x3F80;
// fp32 1.0f little-endian -> first u16 = 0x0000.
// ---------------------------------------------------------------------------
__global__ void detect_k(const void* g, int* flag)
{
    if (threadIdx.x == 0) {
        const unsigned short* u = (const unsigned short*)g;
        *flag = (u[0] == 0x3F80u) ? 1 : 0;
    }
}

// ---------------------------------------------------------------------------
// Embedding: x[t, j] = sum_e tok_emb[batch[t], e] * W[e, j] + b[j] + pe(l, j)
// ---------------------------------------------------------------------------
__global__ __launch_bounds__(256)
void embed_k(const int* __restrict__ batch, const void* __restrict__ emb,
             const void* __restrict__ W, const void* __restrict__ bvec,
             float* __restrict__ x, const int* __restrict__ flagp)
{
    int fb = *flagp;
    int tkn = blockIdx.x;          // 0..2047  (b*512 + l)
    int l = tkn & 511;
    int idx = batch[tkn];
    __shared__ float e[E_DIM];
    int t = threadIdx.x;
    if (t < E_DIM) e[t] = ldin(emb, (long)idx * E_DIM + t, fb);
    __syncthreads();
    for (int j = t; j < H_DIM; j += 256) {
        float s = 0.f;
        #pragma unroll 8
        for (int k = 0; k < E_DIM; ++k) s += e[k] * ldin(W, (long)k * H_DIM + j, fb);
        s += ldin(bvec, j, fb);
        int m2 = j & ~1;
        float inv = powf(10000.f, -(float)m2 / 768.f);
        float tt = (float)l * inv;
        s += (j & 1) ? cosf(tt) : sinf(tt);
        x[(long)tkn * H_DIM + j] = s;
    }
}

// ---------------------------------------------------------------------------
// Generic tiled GEMM: C = A(MxK)*B(KxN) [+bias] [gelu]; fp32 accum.
// aoff0/boff0/coff0: base element offsets. amode/bmode: 1 = input tensor
// (dtype per flag), 0 = fp32 workspace. Batched via z: z1=z/nb2, z2=z%nb2.
// ---------------------------------------------------------------------------
__global__ __launch_bounds__(256)
void gemm_k(const void* __restrict__ Ap, long aoff0, int lda, long sA1, long sA2,
            const void* __restrict__ Bp, long boff0, int ldb, long sB1, long sB2,
            float* __restrict__ Cp, long coff0, int ldc, long sC1, long sC2,
            int M, int N, int K, int nb2,
            const void* __restrict__ bias, long biasoff, int act,
            int amode, int bmode, const int* __restrict__ flagp)
{
    __shared__ float As[64][17];
    __shared__ float Bs[16][65];
    int fb = *flagp;
    int abf = amode ? fb : 0;
    int bbf = bmode ? fb : 0;
    int z = blockIdx.z;
    int z1 = z / nb2, z2 = z - z1 * nb2;
    long aoff = aoff0 + z1 * sA1 + z2 * sA2;
    long boff = boff0 + z1 * sB1 + z2 * sB2;
    float* C = Cp + coff0 + z1 * sC1 + z2 * sC2;
    int I0 = blockIdx.y * 64, J0 = blockIdx.x * 64;
    int t = threadIdx.x;
    int ty = t >> 4, tx = t & 15;
    float acc[4][4] = {};

    for (int k0 = 0; k0 < K; k0 += 16) {
        {
            int r = t >> 2, c = (t & 3) * 4;
            long base = aoff + (long)(I0 + r) * lda + (k0 + c);
            #pragma unroll
            for (int u = 0; u < 4; ++u)
                As[r][c + u] = ldin(Ap, base + u, abf);
        }
        {
            int r = t >> 4, c = (t & 15) * 4;
            long base = boff + (long)(k0 + r) * ldb + (J0 + c);
            #pragma unroll
            for (int u = 0; u < 4; ++u)
                Bs[r][c + u] = ldin(Bp, base + u, bbf);
        }
        __syncthreads();
        #pragma unroll
        for (int kk = 0; kk < 16; ++kk) {
            float a0 = As[ty * 4 + 0][kk];
            float a1 = As[ty * 4 + 1][kk];
            float a2 = As[ty * 4 + 2][kk];
            float a3 = As[ty * 4 + 3][kk];
            float b0 = Bs[kk][tx * 4 + 0];
            float b1 = Bs[kk][tx * 4 + 1];
            float b2 = Bs[kk][tx * 4 + 2];
            float b3 = Bs[kk][tx * 4 + 3];
            acc[0][0] += a0 * b0; acc[0][1] += a0 * b1; acc[0][2] += a0 * b2; acc[0][3] += a0 * b3;
            acc[1][0] += a1 * b0; acc[1][1] += a1 * b1; acc[1][2] += a1 * b2; acc[1][3] += a1 * b3;
            acc[2][0] += a2 * b0; acc[2][1] += a2 * b1; acc[2][2] += a2 * b2; acc[2][3] += a2 * b3;
            acc[3][0] += a3 * b0; acc[3][1] += a3 * b1; acc[3][2] += a3 * b2; acc[3][3] += a3 * b3;
        }
        __syncthreads();
    }
    #pragma unroll
    for (int i = 0; i < 4; ++i) {
        int row = I0 + ty * 4 + i;
        #pragma unroll
        for (int j = 0; j < 4; ++j) {
            int col = J0 + tx * 4 + j;
            float v = acc[i][j];
            if (bias) v += ldin(bias, biasoff + col, fb);
            if (act == 1) v = v / (1.f + expf(-1.702f * v));
            C[(long)row * ldc + col] = v;
        }
    }
}

// ---------------------------------------------------------------------------
__global__ __launch_bounds__(256)
void kbias_k(const float* __restrict__ kmat, const void* __restrict__ cb,
             long cboff, float* __restrict__ kk, const int* __restrict__ flagp)
{
    int fb = *flagp;
    int idx = blockIdx.x * 256 + threadIdx.x;       // 24576
    int j = idx & 511;
    int z = idx >> 9;
    int h = z % 12, b = z / 12;
    const float* kr = kmat + ((long)(b * 512 + j)) * H_DIM + h * 64;
    float s = 0.f;
    #pragma unroll 8
    for (int d = 0; d < 64; ++d) s += kr[d] * ldin(cb, cboff + h * 64 + d, fb);
    kk[idx] = s;
}

__global__ __launch_bounds__(256)
void drow_k(const float* __restrict__ Qp, const void* __restrict__ pb,
            long pboff, float* __restrict__ Drow, const int* __restrict__ flagp)
{
    int fb = *flagp;
    int idx = blockIdx.x * 256 + threadIdx.x;       // 6144
    int j = idx & 511;
    int h = idx >> 9;
    const float* qr = Qp + (long)j * H_DIM + h * 64;
    float s = 0.f;
    #pragma unroll 8
    for (int d = 0; d < 64; ++d) s += qr[d] * ldin(pb, pboff + h * 64 + d, fb);
    Drow[h * 512 + j] = s;
}

// ---------------------------------------------------------------------------
__global__ __launch_bounds__(256)
void score_k(const float* __restrict__ q, const float* __restrict__ k,
             const float* __restrict__ Qp, const float* __restrict__ kkb,
             const float* __restrict__ Drow, float* __restrict__ S, int bq)
{
    __shared__ float qs[32][65];
    __shared__ float ks[32][65];
    __shared__ float Qs[63][65];
    int h = blockIdx.z;
    int I0 = blockIdx.y * 32, J0 = blockIdx.x * 32;
    int t = threadIdx.x;

    for (int i = t; i < 32 * 64; i += 256) {
        int r = i >> 6, c = i & 63;
        qs[r][c] = q[((long)(bq * 512 + I0 + r)) * H_DIM + h * 64 + c];
    }
    for (int i = t; i < 32 * 64; i += 256) {
        int r = i >> 6, c = i & 63;
        ks[r][c] = k[((long)(bq * 512 + J0 + r)) * H_DIM + h * 64 + c];
    }
    int r0 = 511 - I0 + J0;
    for (int i = t; i < 63 * 64; i += 256) {
        int rr = i >> 6, c = i & 63;
        int r = r0 - 31 + rr;
        r = min(511, max(0, r));
        Qs[rr][c] = Qp[(long)r * H_DIM + h * 64 + c];
    }
    __syncthreads();

    int tx = t & 31;
    int tyb = (t >> 5) * 4;
    float a1[4] = {}, a2[4] = {};
    #pragma unroll
    for (int i = 0; i < 4; ++i) {
        int ti = tyb + i;
        float s1 = 0.f, s2 = 0.f;
        const float* qrow = qs[ti];
        const float* krow = ks[tx];
        const float* Qrow = Qs[tx - ti + 31];
        #pragma unroll 8
        for (int d = 0; d < 64; ++d) {
            float qa = qrow[d];
            s1 += qa * krow[d];
            s2 += qa * Qrow[d];
        }
        a1[i] = s1; a2[i] = s2;
    }
    #pragma unroll
    for (int i = 0; i < 4; ++i) {
        int gi = I0 + tyb + i, gj = J0 + tx;
        float v = a1[i] + kkb[(bq * 12 + h) * 512 + gj];
        if (gj <= gi) {
            int r = 511 - gi + gj;
            v += a2[i] + Drow[h * 512 + r];
        }
        S[((long)h * 512 + gi) * 512 + gj] = v;
    }
}

// ---------------------------------------------------------------------------
__global__ __launch_bounds__(256)
void softmax_k(float* __restrict__ S)
{
    long row = blockIdx.x;
    float* p = S + row * 512;
    int t = threadIdx.x;
    float v0 = p[t], v1 = p[t + 256];
    __shared__ float red[256];
    red[t] = fmaxf(v0, v1);
    __syncthreads();
    for (int s = 128; s > 0; s >>= 1) { if (t < s) red[t] = fmaxf(red[t], red[t + s]); __syncthreads(); }
    float mx = red[0];
    __syncthreads();
    float e0 = __expf(v0 - mx), e1 = __expf(v1 - mx);
    red[t] = e0 + e1;
    __syncthreads();
    for (int s = 128; s > 0; s >>= 1) { if (t < s) red[t] += red[t + s]; __syncthreads(); }
    float inv = 1.f / red[0];
    p[t] = e0 * inv;
    p[t + 256] = e1 * inv;
}

// ---------------------------------------------------------------------------
// out = LN(y [+resid] [+bias]) * g + b ; offsets are element indices into
// the (possibly bf16) input arrays.
// ---------------------------------------------------------------------------
__global__ __launch_bounds__(256)
void ln_k(const float* y, const float* resid,
          const void* bias, long biasoff, const void* g, long goff,
          const void* bta, long boff, float* out, const int* flagp)
{
    int fb = *flagp;
    long row = blockIdx.x;
    const float* yr = y + row * H_DIM;
    int t = threadIdx.x;
    float v[3];
    #pragma unroll
    for (int i = 0; i < 3; ++i) {
        int c = t + i * 256;
        float x = yr[c];
        if (resid) x += resid[row * H_DIM + c];
        if (bias) x += ldin(bias, biasoff + c, fb);
        v[i] = x;
    }
    __shared__ float red[256];
    red[t] = v[0] + v[1] + v[2];
    __syncthreads();
    for (int s = 128; s > 0; s >>= 1) { if (t < s) red[t] += red[t + s]; __syncthreads(); }
    float mu = red[0] / 768.f;
    __syncthreads();
    float d0 = v[0] - mu, d1 = v[1] - mu, d2 = v[2] - mu;
    red[t] = d0 * d0 + d1 * d1 + d2 * d2;
    __syncthreads();
    for (int s = 128; s > 0; s >>= 1) { if (t < s) red[t] += red[t + s]; __syncthreads(); }
    float rs = rsqrtf(red[0] / 768.f + 1e-5f);
    float* outr = out + row * H_DIM;
    float dd[3] = {d0, d1, d2};
    #pragma unroll
    for (int i = 0; i < 3; ++i) {
        int c = t + i * 256;
        outr[c] = dd[i] * rs * ldin(g, goff + c, fb) + ldin(bta, boff + c, fb);
    }
}

// ---------------------------------------------------------------------------
__global__ __launch_bounds__(256)
void sop_k(const float* __restrict__ x, const void* __restrict__ w,
           const void* __restrict__ bias, void* __restrict__ out,
           const int* __restrict__ flagp)
{
    int fb = *flagp;
    int b = blockIdx.x >> 1, o = blockIdx.x & 1;
    int t = threadIdx.x;
    const float* xr = x + (long)b * 512 * H_DIM;
    float s = 0.f;
    for (int c = t; c < H_DIM; c += 256) s += xr[c] * ldin(w, (long)c * 2 + o, fb);
    __shared__ float red[256];
    red[t] = s;
    __syncthreads();
    for (int st = 128; st > 0; st >>= 1) { if (t < st) red[t] += red[t + st]; __syncthreads(); }
    if (t == 0) stout(out, blockIdx.x, red[0] + ldin(bias, o, fb), fb);
}

// ---------------------------------------------------------------------------
__global__ __launch_bounds__(256)
void logits_k(const float* __restrict__ e, const void* __restrict__ emb,
              const void* __restrict__ outb, void* __restrict__ out,
              const int* __restrict__ flagp)
{
    __shared__ float As[32][129];
    __shared__ float Bs[64][129];
    int fb = *flagp;
    int W0 = blockIdx.x * 64, R0 = blockIdx.y * 32;
    int t = threadIdx.x;
    for (int i = t; i < 32 * 128; i += 256) {
        int r = i >> 7, c = i & 127;
        int ri = R0 + r;
        float vv = 0.f;
        if (ri < BATCH * 511) {
            int b = ri / 511, j = ri - b * 511;
            vv = e[((long)(b * 512 + j + 1)) * E_DIM + c];
        }
        As[r][c] = vv;
    }
    for (int i = t; i < 64 * 128; i += 256) {
        int r = i >> 7, c = i & 127;
        int w = W0 + r;
        Bs[r][c] = (w < N_WORD) ? ldin(emb, (long)w * E_DIM + c, fb) : 0.f;
    }
    __syncthreads();
    int tx = t & 15, ty = t >> 4;
    float acc[2][4] = {};
    #pragma unroll 4
    for (int kc = 0; kc < 128; ++kc) {
        float a0 = As[ty * 2 + 0][kc];
        float a1 = As[ty * 2 + 1][kc];
        float b0 = Bs[tx * 4 + 0][kc];
        float b1 = Bs[tx * 4 + 1][kc];
        float b2 = Bs[tx * 4 + 2][kc];
        float b3 = Bs[tx * 4 + 3][kc];
        acc[0][0] += a0 * b0; acc[0][1] += a0 * b1; acc[0][2] += a0 * b2; acc[0][3] += a0 * b3;
        acc[1][0] += a1 * b0; acc[1][1] += a1 * b1; acc[1][2] += a1 * b2; acc[1][3] += a1 * b3;
    }
    #pragma unroll
    for (int i = 0; i < 2; ++i) {
        int ri = R0 + ty * 2 + i;
        if (ri >= BATCH * 511) continue;
        #pragma unroll
        for (int j = 0; j < 4; ++j) {
            int w = W0 + tx * 4 + j;
            if (w < N_WORD)
                stout(out, 8 + (long)ri * N_WORD + w, acc[i][j] + ldin(outb, w, fb), fb);
        }
    }
}

// ---------------------------------------------------------------------------
extern "C" void kernel_launch(void* const* d_in, const int* in_sizes, int n_in,
                              void* d_out, int out_size, void* d_ws, size_t ws_size,
                              hipStream_t stream)
{
    const int*  batch    = (const int*)d_in[0];
    const void* tok_emb  = d_in[2];
    const void* to_hid_w = d_in[3];
    const void* to_hid_b = d_in[4];
    const void* R        = d_in[5];
    const void* Wq       = d_in[6];
    const void* Wke      = d_in[7];
    const void* Wv       = d_in[8];
    const void* Wkr      = d_in[9];
    const void* cb       = d_in[10];
    const void* pb       = d_in[11];
    const void* Wo_w     = d_in[12];
    const void* Wo_b     = d_in[13];
    const void* ln1_g    = d_in[14];
    const void* ln1_b    = d_in[15];
    const void* ff1_w    = d_in[16];
    const void* ff1_b    = d_in[17];
    const void* ff2_w    = d_in[18];
    const void* ff2_b    = d_in[19];
    const void* ln2_g    = d_in[20];
    const void* ln2_b    = d_in[21];
    const void* osp_w    = d_in[22];
    const void* osp_b    = d_in[23];
    const void* mlm_w    = d_in[24];
    const void* mlm_b    = d_in[25];
    const void* mlm_ln_g = d_in[26];
    const void* mlm_ln_b = d_in[27];
    const void* to_emb_w = d_in[28];
    const void* to_emb_b = d_in[29];
    const void* out_b    = d_in[30];

    float* ws  = (float*)d_ws;
    float* x   = ws;
    float* qb  = ws + 1572864;
    float* kb  = ws + 3145728;
    float* vb  = ws + 4718592;
    float* tmp = ws + 6291456;
    float* Qp  = ws + 7864320;
    float* kkb = ws + 8257536;
    float* Dr  = ws + 8282112;
    float* U   = ws + 8288256;
    int*   flg = (int*)(ws + 11433984);
    float* eb  = qb;

    detect_k<<<1, 64, 0, stream>>>(ln1_g, flg);

    embed_k<<<2048, 256, 0, stream>>>(batch, tok_emb, to_hid_w, to_hid_b, x, flg);

    for (int i = 0; i < N_LAYERS; ++i) {
        long oW  = (long)i * 768 * 768;
        long o768 = (long)i * 768;
        long oR  = (long)i * 512 * 768;
        long oF1 = (long)i * 768 * 3072;
        long oF2 = (long)i * 3072 * 768;

        gemm_k<<<dim3(12, 32, 1), 256, 0, stream>>>(
            x, 0, 768, 0, 0, Wq, oW, 768, 0, 0, qb, 0, 768, 0, 0,
            2048, 768, 768, 1, nullptr, 0, 0, 0, 1, flg);
        gemm_k<<<dim3(12, 32, 1), 256, 0, stream>>>(
            x, 0, 768, 0, 0, Wke, oW, 768, 0, 0, kb, 0, 768, 0, 0,
            2048, 768, 768, 1, nullptr, 0, 0, 0, 1, flg);
        gemm_k<<<dim3(12, 32, 1), 256, 0, stream>>>(
            x, 0, 768, 0, 0, Wv, oW, 768, 0, 0, vb, 0, 768, 0, 0,
            2048, 768, 768, 1, nullptr, 0, 0, 0, 1, flg);
        gemm_k<<<dim3(12, 8, 1), 256, 0, stream>>>(
            R, oR, 768, 0, 0, Wkr, oW, 768, 0, 0, Qp, 0, 768, 0, 0,
            512, 768, 768, 1, nullptr, 0, 0, 1, 1, flg);

        kbias_k<<<96, 256, 0, stream>>>(kb, cb, o768, kkb, flg);
        drow_k<<<24, 256, 0, stream>>>(Qp, pb, o768, Dr, flg);

        for (int bq = 0; bq < BATCH; ++bq) {
            score_k<<<dim3(16, 16, 12), 256, 0, stream>>>(qb, kb, Qp, kkb, Dr, U, bq);
            softmax_k<<<6144, 256, 0, stream>>>(U);
            gemm_k<<<dim3(1, 8, 12), 256, 0, stream>>>(
                U, 0, 512, 0, 262144, vb, (long)bq * 393216, 768, 0, 64,
                tmp, (long)bq * 393216, 768, 0, 64,
                512, 64, 512, 12, nullptr, 0, 0, 0, 0, flg);
        }

        gemm_k<<<dim3(12, 32, 1), 256, 0, stream>>>(
            tmp, 0, 768, 0, 0, Wo_w, oW, 768, 0, 0, qb, 0, 768, 0, 0,
            2048, 768, 768, 1, nullptr, 0, 0, 0, 1, flg);
        ln_k<<<2048, 256, 0, stream>>>(qb, x, Wo_b, o768, ln1_g, o768, ln1_b, o768, x, flg);

        for (int bq = 0; bq < BATCH; ++bq) {
            gemm_k<<<dim3(48, 8, 1), 256, 0, stream>>>(
                x, (long)bq * 393216, 768, 0, 0, ff1_w, oF1, 3072, 0, 0, U, 0, 3072, 0, 0,
                512, 3072, 768, 1, ff1_b, (long)i * 3072, 1, 0, 1, flg);
            gemm_k<<<dim3(12, 8, 1), 256, 0, stream>>>(
                U, 0, 3072, 0, 0, ff2_w, oF2, 768, 0, 0, qb, (long)bq * 393216, 768, 0, 0,
                512, 768, 3072, 1, nullptr, 0, 0, 0, 1, flg);
        }
        ln_k<<<2048, 256, 0, stream>>>(qb, x, ff2_b, o768, ln2_g, o768, ln2_b, o768, x, flg);
    }

    sop_k<<<8, 256, 0, stream>>>(x, osp_w, osp_b, d_out, flg);

    gemm_k<<<dim3(12, 32, 1), 256, 0, stream>>>(
        x, 0, 768, 0, 0, mlm_w, 0, 768, 0, 0, tmp, 0, 768, 0, 0,
        2048, 768, 768, 1, mlm_b, 0, 1, 0, 1, flg);
    ln_k<<<2048, 256, 0, stream>>>(tmp, nullptr, nullptr, 0, mlm_ln_g, 0, mlm_ln_b, 0, kb, flg);
    gemm_k<<<dim3(2, 32, 1), 256, 0, stream>>>(
        kb, 0, 768, 0, 0, to_emb_w, 0, 128, 0, 0, eb, 0, 128, 0, 0,
        2048, 128, 768, 1, to_emb_b, 0, 0, 0, 1, flg);
    logits_k<<<dim3(469, 64, 1), 256, 0, stream>>>(eb, tok_emb, out_b, d_out, flg);
}